// Round 10
// baseline (148.821 us; speedup 1.0000x reference)
//
#include <hip/hip_runtime.h>
#include <hip/hip_bf16.h>

// GeneratorSDF: latent-conditioned MLP SDF on a 128^3 grid (fp32 I/O).
// dims: 67 -> 128 -> 64 -> 32 -> 1 (relu, relu, relu, sigmoid)
//
// R10 = R9 + register-hoisted h1 tables. R9 post-mortem: cutting VALU 25%
// (packed ops) was duration-neutral -> critical path is DS latency, namely
// 16 ng-invariant ds_read_b128 per ng re-issued every iteration (compiler
// didn't LICM them). Hoist s_base/s_wc slices into 64 VGPRs, loaded once:
// in-loop DS ops drop 23 -> 7 per ng. Accept 2 waves/SIMD (VGPR ~200);
// occupancy evidence (R4/R8: measured = 0.4 x VGPR-model) says we were
// VGPR-limited at 4 waves/SIMD; trade residency for a much shorter stall
// chain. Watch FETCH_SIZE for spills (R7 lesson).
// Structure (verified R8): software-pipelined h2 double-buffer (A(ng) writes
// slot ng&1, B(ng-1) reads the other), deferred batched epilogue, 512
// pts/block, LDS union, __launch_bounds__(256,2).
// MFMA layouts (verified m89/m91): A[m=lane&15][k=quad*8+j],
// B[k=quad*8+j][n=lane&15], C/D row=quad*4+reg, col=lane&15.

#define NPTS (128 * 128 * 128)

typedef float f32x4_t __attribute__((ext_vector_type(4)));
typedef float f32x2_t __attribute__((ext_vector_type(2)));
typedef short bf16x8_t __attribute__((ext_vector_type(8)));

__device__ __forceinline__ unsigned pk2(float lo, float hi) {
    __hip_bfloat162 p = __float22bfloat162_rn(make_float2(lo, hi));
    unsigned u;
    __builtin_memcpy(&u, &p, sizeof(u));
    return u;
}

__global__ __launch_bounds__(256, 2) void mlp_kernel(
    const float* __restrict__ x,  const float* __restrict__ W1,
    const float* __restrict__ b1, const float* __restrict__ W2,
    const float* __restrict__ b2, const float* __restrict__ W3,
    const float* __restrict__ b3, const float* __restrict__ W4,
    const float* __restrict__ b4, float* __restrict__ out) {
    __shared__ __align__(16) float s_base[4][128];  // per-wave j: base+wa*pa+wb*pb_j
    __shared__ __align__(16) float s_wc[128];       // wc[k] (j-independent)
    __shared__ __align__(16) float s_b2[64];
    __shared__ __align__(16) float s_b3[32];
    __shared__ __align__(16) float s_w4[32];
    // Union (26.6 KB): staging = w2a[16][64][8] (shorts 0..8191) + w3a[4][64][8]
    // (8192..10239); runtime = h2 slots [w][2][16][72] (0..9215) + z floats
    // (shorts 9216..13311 = float[4][8][16][4] : w*512 + ng*64 + i*4 + q).
    __shared__ __align__(16) unsigned short s_u[13312];

    const int t = threadIdx.x;
    const int w = t >> 6;
    const int lane = t & 63;
    const int quad = lane >> 4;
    const int l15 = lane & 15;
    const float step = 2.0f / 127.0f;

    // ================= per-block prep =================
    if (t < 128) {
        const float* w1row = W1 + t * 67;
        float s = b1[t];
#pragma unroll 8
        for (int c = 0; c < 64; ++c) s = fmaf(w1row[c], x[c], s);
        const float wa = w1row[64], wb = w1row[65], wc = w1row[66];
        const float pa = -1.0f + step * (float)(blockIdx.x >> 5);
        const float base = fmaf(wa, pa, s);
        const int gj0 = (blockIdx.x * 4) & 127;  // multiple of 4, gj0+3 <= 127
        s_wc[t] = wc;
#pragma unroll
        for (int j = 0; j < 4; ++j) {
            const float pb = -1.0f + step * (float)(gj0 + j);
            s_base[j][t] = fmaf(wb, pb, base);
        }
    }
    // W2 [64][128] -> bf16 A-frag staging
    const float2* W2v = (const float2*)W2;
#pragma unroll
    for (int it = 0; it < 16; ++it) {
        int pidx = t + 256 * it;
        int idx2 = pidx * 2;
        int o = idx2 >> 7, k = idx2 & 127;
        int mt = o >> 4, lm = o & 15;
        int kb = k >> 5, q = (k >> 3) & 3, jj = k & 7;
        float2 v = W2v[pidx];
        *(unsigned*)&s_u[(mt * 4 + kb) * 512 + (q * 16 + lm) * 8 + jj] = pk2(v.x, v.y);
    }
    // W3 [32][64] -> bf16 A-frag staging
    const float2* W3v = (const float2*)W3;
#pragma unroll
    for (int it = 0; it < 4; ++it) {
        int pidx = t + 256 * it;
        int idx2 = pidx * 2;
        int o = idx2 >> 6, k = idx2 & 63;
        int mt = o >> 4, lm = o & 15;
        int kb = k >> 5, q = (k >> 3) & 3, jj = k & 7;
        float2 v = W3v[pidx];
        *(unsigned*)&s_u[8192 + (mt * 2 + kb) * 512 + (q * 16 + lm) * 8 + jj] = pk2(v.x, v.y);
    }
    if (t < 64) s_b2[t] = b2[t];
    if (t < 32) {
        s_b3[t] = b3[t];
        s_w4[t] = W4[t];
    }
    const float bias4 = b4[0];
    __syncthreads();

    // ================= per-wave fragment preload =================
    bf16x8_t a2[16];
#pragma unroll
    for (int f = 0; f < 16; ++f) a2[f] = *(const bf16x8_t*)&s_u[f * 512 + lane * 8];
    bf16x8_t a3[4];
#pragma unroll
    for (int f = 0; f < 4; ++f) a3[f] = *(const bf16x8_t*)&s_u[8192 + f * 512 + lane * 8];
    float4 b2q[4];
#pragma unroll
    for (int mt = 0; mt < 4; ++mt) b2q[mt] = *(const float4*)&s_b2[mt * 16 + quad * 4];
    float4 b3q[2];
    f32x2_t w4lo[2], w4hi[2];
#pragma unroll
    for (int mt = 0; mt < 2; ++mt) {
        b3q[mt] = *(const float4*)&s_b3[mt * 16 + quad * 4];
        float4 wq = *(const float4*)&s_w4[mt * 16 + quad * 4];
        w4lo[mt][0] = wq.x; w4lo[mt][1] = wq.y;
        w4hi[mt][0] = wq.z; w4hi[mt][1] = wq.w;
    }
    // ---- hoisted h1 tables: ng-invariant, 16 b128 reads ONCE (was 16/ng) ----
    const float* bj = &s_base[w][0];
    f32x2_t rb[16], rw[16];
#pragma unroll
    for (int kb = 0; kb < 4; ++kb) {
#pragma unroll
        for (int half = 0; half < 2; ++half) {
            const int o = kb * 32 + quad * 8 + half * 4;
            float4 bs = *(const float4*)&bj[o];
            float4 wc4 = *(const float4*)&s_wc[o];
            const int i = (kb * 2 + half) * 2;
            rb[i] = (f32x2_t){bs.x, bs.y};
            rb[i + 1] = (f32x2_t){bs.z, bs.w};
            rw[i] = (f32x2_t){wc4.x, wc4.y};
            rw[i + 1] = (f32x2_t){wc4.z, wc4.w};
        }
    }
    __syncthreads();  // union handoff: staging -> h2/z scratch

    const int sw = (l15 & 1) * 32;                    // h2 channel swizzle (shorts)
    unsigned short* h2w = &s_u[w * 2 * 1152];         // 2 slots x 16 pts x 72 shorts
    float* zf = (float*)&s_u[9216];                   // [w][ng][i][q]
    const f32x2_t zero2 = {0.0f, 0.0f};

    // B-phase: layer 3 + w4-dot for point-group pg (reads h2 slot pg&1)
    auto bphase = [&](int pg) {
        const unsigned short* pslot = h2w + (pg & 1) * 1152 + l15 * 72;
        bf16x8_t b3f0 = *(const bf16x8_t*)&pslot[(0 ^ sw) + quad * 8];
        bf16x8_t b3f1 = *(const bf16x8_t*)&pslot[(32 ^ sw) + quad * 8];
        f32x2_t z2 = zero2;
#pragma unroll
        for (int mt = 0; mt < 2; ++mt) {
            f32x4_t c;
            c[0] = b3q[mt].x; c[1] = b3q[mt].y; c[2] = b3q[mt].z; c[3] = b3q[mt].w;
            c = __builtin_amdgcn_mfma_f32_16x16x32_bf16(a3[mt * 2 + 0], b3f0, c, 0, 0, 0);
            c = __builtin_amdgcn_mfma_f32_16x16x32_bf16(a3[mt * 2 + 1], b3f1, c, 0, 0, 0);
            f32x2_t h01 = __builtin_elementwise_max((f32x2_t){c[0], c[1]}, zero2);
            f32x2_t h23 = __builtin_elementwise_max((f32x2_t){c[2], c[3]}, zero2);
            z2 = __builtin_elementwise_fma(w4lo[mt], h01, z2);
            z2 = __builtin_elementwise_fma(w4hi[mt], h23, z2);
        }
        zf[w * 512 + pg * 64 + l15 * 4 + quad] = z2[0] + z2[1];
    };

    // ========== pipelined main loop: A(ng) then B(ng-1) ==========
#pragma unroll 2
    for (int ng = 0; ng < 8; ++ng) {
        const float pc = fmaf(step, (float)(ng * 16 + l15), -1.0f);
        const f32x2_t pc2 = {pc, pc};

        // ---- A: h1 into B-fragments, all inputs in registers ----
        bf16x8_t bfrag[4];
#pragma unroll
        for (int kb = 0; kb < 4; ++kb) {
            union { bf16x8_t v; unsigned u[4]; } bb;
#pragma unroll
            for (int half = 0; half < 2; ++half) {
                const int i = (kb * 2 + half) * 2;
                f32x2_t h01 = __builtin_elementwise_fma(rw[i], pc2, rb[i]);
                f32x2_t h23 = __builtin_elementwise_fma(rw[i + 1], pc2, rb[i + 1]);
                h01 = __builtin_elementwise_max(h01, zero2);
                h23 = __builtin_elementwise_max(h23, zero2);
                bb.u[half * 2 + 0] = pk2(h01[0], h01[1]);
                bb.u[half * 2 + 1] = pk2(h23[0], h23[1]);
            }
            bfrag[kb] = bb.v;
        }
        // ---- A: layer 2 MFMA, bias in C-init ----
        f32x4_t acc2[4];
#pragma unroll
        for (int mt = 0; mt < 4; ++mt) {
            f32x4_t c;
            c[0] = b2q[mt].x; c[1] = b2q[mt].y; c[2] = b2q[mt].z; c[3] = b2q[mt].w;
#pragma unroll
            for (int kb = 0; kb < 4; ++kb)
                c = __builtin_amdgcn_mfma_f32_16x16x32_bf16(a2[mt * 4 + kb], bfrag[kb], c, 0, 0, 0);
            acc2[mt] = c;
        }
        // ---- A: packed relu + pack + write h2 slot ng&1 ----
        unsigned short* slot = h2w + (ng & 1) * 1152 + l15 * 72;
#pragma unroll
        for (int mt = 0; mt < 4; ++mt) {
            f32x2_t v01 = __builtin_elementwise_max((f32x2_t){acc2[mt][0], acc2[mt][1]}, zero2);
            f32x2_t v23 = __builtin_elementwise_max((f32x2_t){acc2[mt][2], acc2[mt][3]}, zero2);
            uint2 pk;
            pk.x = pk2(v01[0], v01[1]);
            pk.y = pk2(v23[0], v23[1]);
            *(uint2*)&slot[(mt * 16 + quad * 4) ^ sw] = pk;
        }
        // ---- B for previous group (write->read distance = one full A) ----
        if (ng > 0) bphase(ng - 1);
    }
    bphase(7);  // drain

    // ========== phase C: batched reduce + sigmoid + coalesced store ==========
#pragma unroll
    for (int half = 0; half < 2; ++half) {
        const int p = lane + 64 * half;       // point within this wave's 128
        const int ng = p >> 4, i = p & 15;
        float4 v = *(const float4*)&zf[w * 512 + ng * 64 + i * 4];
        float z = (v.x + v.y) + (v.z + v.w) + bias4;
        float sig = 1.0f / (1.0f + __expf(-z));
        out[blockIdx.x * 512 + w * 128 + p] = sig;
    }
}

extern "C" void kernel_launch(void* const* d_in, const int* in_sizes, int n_in,
                              void* d_out, int out_size, void* d_ws, size_t ws_size,
                              hipStream_t stream) {
    mlp_kernel<<<NPTS / 512, 256, 0, stream>>>(
        (const float*)d_in[0], (const float*)d_in[1], (const float*)d_in[2],
        (const float*)d_in[3], (const float*)d_in[4], (const float*)d_in[5],
        (const float*)d_in[6], (const float*)d_in[7], (const float*)d_in[8],
        (float*)d_out);
}

// Round 11
// 141.460 us; speedup vs baseline: 1.0520x; 1.0520x over previous
//
#include <hip/hip_runtime.h>
#include <hip/hip_bf16.h>

// GeneratorSDF: latent-conditioned MLP SDF on a 128^3 grid (fp32 I/O).
// dims: 67 -> 128 -> 64 -> 32 -> 1 (relu, relu, relu, sigmoid)
//
// R11 = R9 structure with 2048 pts/block (grid 1024, 32 ng/wave).
// R10 post-mortem: VGPR stayed 112 -> compiler sank the "hoisted" tables back
// into the loop; R8/R9/R10 all ~94us. Counter arithmetic: ~35% of VALU work is
// PER-BLOCK PREP (scattered W1 fold + W2/W3 fragment staging), repeated by
// 4096 blocks. This round amortizes it 4x. Single-variable change.
//  - s_base[16][128]: 16 pb rows per block; wave reads row w*4 + (ng>>3).
//  - phase C runs per 8-ng batch (zf reuse is per-wave in-order DS, safe).
//  - pipeline/h2/zf/union byte-identical to R8/R9 (verified).
// MFMA layouts (verified m89/m91): A[m=lane&15][k=quad*8+j],
// B[k=quad*8+j][n=lane&15], C/D row=quad*4+reg, col=lane&15.

#define NPTS (128 * 128 * 128)

typedef float f32x4_t __attribute__((ext_vector_type(4)));
typedef float f32x2_t __attribute__((ext_vector_type(2)));
typedef short bf16x8_t __attribute__((ext_vector_type(8)));

__device__ __forceinline__ unsigned pk2(float lo, float hi) {
    __hip_bfloat162 p = __float22bfloat162_rn(make_float2(lo, hi));
    unsigned u;
    __builtin_memcpy(&u, &p, sizeof(u));
    return u;
}

__global__ __launch_bounds__(256, 2) void mlp_kernel(
    const float* __restrict__ x,  const float* __restrict__ W1,
    const float* __restrict__ b1, const float* __restrict__ W2,
    const float* __restrict__ b2, const float* __restrict__ W3,
    const float* __restrict__ b3, const float* __restrict__ W4,
    const float* __restrict__ b4, float* __restrict__ out) {
    __shared__ __align__(16) float s_base[16][128];  // j-row: base+wa*pa+wb*pb_j
    __shared__ __align__(16) float s_wc[128];        // wc[k]
    __shared__ __align__(16) float s_b2[64];
    __shared__ __align__(16) float s_b3[32];
    __shared__ __align__(16) float s_w4[32];
    // Union (26.6 KB): staging = w2a[16][64][8] (shorts 0..8191) + w3a[4][64][8]
    // (8192..10239); runtime = h2 slots [w][2][16][72] (0..9215) + z floats
    // (shorts 9216..13311 = float[4][8][16][4] : w*512 + pg*64 + i*4 + q).
    __shared__ __align__(16) unsigned short s_u[13312];

    const int t = threadIdx.x;
    const int w = t >> 6;
    const int lane = t & 63;
    const int quad = lane >> 4;
    const int l15 = lane & 15;
    const float step = 2.0f / 127.0f;

    // ================= per-block prep =================
    if (t < 128) {
        const float* w1row = W1 + t * 67;
        float s = b1[t];
#pragma unroll 8
        for (int c = 0; c < 64; ++c) s = fmaf(w1row[c], x[c], s);
        const float wa = w1row[64], wb = w1row[65], wc = w1row[66];
        const float pa = -1.0f + step * (float)(blockIdx.x >> 3);   // gi
        const float base = fmaf(wa, pa, s);
        const int gj0 = (blockIdx.x & 7) * 16;
        s_wc[t] = wc;
#pragma unroll
        for (int j = 0; j < 16; ++j) {
            const float pb = -1.0f + step * (float)(gj0 + j);
            s_base[j][t] = fmaf(wb, pb, base);
        }
    }
    // W2 [64][128] -> bf16 A-frag staging
    const float2* W2v = (const float2*)W2;
#pragma unroll
    for (int it = 0; it < 16; ++it) {
        int pidx = t + 256 * it;
        int idx2 = pidx * 2;
        int o = idx2 >> 7, k = idx2 & 127;
        int mt = o >> 4, lm = o & 15;
        int kb = k >> 5, q = (k >> 3) & 3, jj = k & 7;
        float2 v = W2v[pidx];
        *(unsigned*)&s_u[(mt * 4 + kb) * 512 + (q * 16 + lm) * 8 + jj] = pk2(v.x, v.y);
    }
    // W3 [32][64] -> bf16 A-frag staging
    const float2* W3v = (const float2*)W3;
#pragma unroll
    for (int it = 0; it < 4; ++it) {
        int pidx = t + 256 * it;
        int idx2 = pidx * 2;
        int o = idx2 >> 6, k = idx2 & 63;
        int mt = o >> 4, lm = o & 15;
        int kb = k >> 5, q = (k >> 3) & 3, jj = k & 7;
        float2 v = W3v[pidx];
        *(unsigned*)&s_u[8192 + (mt * 2 + kb) * 512 + (q * 16 + lm) * 8 + jj] = pk2(v.x, v.y);
    }
    if (t < 64) s_b2[t] = b2[t];
    if (t < 32) {
        s_b3[t] = b3[t];
        s_w4[t] = W4[t];
    }
    const float bias4 = b4[0];
    __syncthreads();

    // ================= per-wave fragment preload =================
    bf16x8_t a2[16];
#pragma unroll
    for (int f = 0; f < 16; ++f) a2[f] = *(const bf16x8_t*)&s_u[f * 512 + lane * 8];
    bf16x8_t a3[4];
#pragma unroll
    for (int f = 0; f < 4; ++f) a3[f] = *(const bf16x8_t*)&s_u[8192 + f * 512 + lane * 8];
    float4 b2q[4];
#pragma unroll
    for (int mt = 0; mt < 4; ++mt) b2q[mt] = *(const float4*)&s_b2[mt * 16 + quad * 4];
    float4 b3q[2];
    f32x2_t w4lo[2], w4hi[2];
#pragma unroll
    for (int mt = 0; mt < 2; ++mt) {
        b3q[mt] = *(const float4*)&s_b3[mt * 16 + quad * 4];
        float4 wq = *(const float4*)&s_w4[mt * 16 + quad * 4];
        w4lo[mt][0] = wq.x; w4lo[mt][1] = wq.y;
        w4hi[mt][0] = wq.z; w4hi[mt][1] = wq.w;
    }
    __syncthreads();  // union handoff: staging -> h2/z scratch

    const int sw = (l15 & 1) * 32;                    // h2 channel swizzle (shorts)
    unsigned short* h2w = &s_u[w * 2 * 1152];         // 2 slots x 16 pts x 72 shorts
    float* zf = (float*)&s_u[9216];                   // [w][pg&7][i][q]
    const f32x2_t zero2 = {0.0f, 0.0f};
    const int outbase = blockIdx.x * 2048 + w * 512;

    // B-phase: layer 3 + w4-dot for point-group pg (reads h2 slot pg&1)
    auto bphase = [&](int pg) {
        const unsigned short* pslot = h2w + (pg & 1) * 1152 + l15 * 72;
        bf16x8_t b3f0 = *(const bf16x8_t*)&pslot[(0 ^ sw) + quad * 8];
        bf16x8_t b3f1 = *(const bf16x8_t*)&pslot[(32 ^ sw) + quad * 8];
        f32x2_t z2 = zero2;
#pragma unroll
        for (int mt = 0; mt < 2; ++mt) {
            f32x4_t c;
            c[0] = b3q[mt].x; c[1] = b3q[mt].y; c[2] = b3q[mt].z; c[3] = b3q[mt].w;
            c = __builtin_amdgcn_mfma_f32_16x16x32_bf16(a3[mt * 2 + 0], b3f0, c, 0, 0, 0);
            c = __builtin_amdgcn_mfma_f32_16x16x32_bf16(a3[mt * 2 + 1], b3f1, c, 0, 0, 0);
            f32x2_t h01 = __builtin_elementwise_max((f32x2_t){c[0], c[1]}, zero2);
            f32x2_t h23 = __builtin_elementwise_max((f32x2_t){c[2], c[3]}, zero2);
            z2 = __builtin_elementwise_fma(w4lo[mt], h01, z2);
            z2 = __builtin_elementwise_fma(w4hi[mt], h23, z2);
        }
        zf[w * 512 + (pg & 7) * 64 + l15 * 4 + quad] = z2[0] + z2[1];
    };
    // phase C: batched reduce + sigmoid + coalesced store for an 8-ng batch
    auto cphase = [&](int batch) {
#pragma unroll
        for (int half = 0; half < 2; ++half) {
            const int p = lane + 64 * half;   // point within this batch's 128
            const int pg = p >> 4, i = p & 15;
            float4 v = *(const float4*)&zf[w * 512 + pg * 64 + i * 4];
            float z = (v.x + v.y) + (v.z + v.w) + bias4;
            out[outbase + batch * 128 + p] = 1.0f / (1.0f + __expf(-z));
        }
    };

    // ========== pipelined main loop: A(ng) then B(ng-1) ==========
#pragma unroll 2
    for (int ng = 0; ng < 32; ++ng) {
        const float* dj = &s_base[w * 4 + (ng >> 3)][0];
        const float pc = fmaf(step, (float)(((ng & 7) * 16) + l15), -1.0f);
        const f32x2_t pc2 = {pc, pc};

        // ---- A: h1 into B-fragments via packed fma/max ----
        bf16x8_t bfrag[4];
#pragma unroll
        for (int kb = 0; kb < 4; ++kb) {
            union { bf16x8_t v; unsigned u[4]; } bb;
#pragma unroll
            for (int half = 0; half < 2; ++half) {
                const int o = kb * 32 + quad * 8 + half * 4;
                float4 bs = *(const float4*)&dj[o];
                float4 wc4 = *(const float4*)&s_wc[o];
                f32x2_t h01 = __builtin_elementwise_fma(
                    (f32x2_t){wc4.x, wc4.y}, pc2, (f32x2_t){bs.x, bs.y});
                f32x2_t h23 = __builtin_elementwise_fma(
                    (f32x2_t){wc4.z, wc4.w}, pc2, (f32x2_t){bs.z, bs.w});
                h01 = __builtin_elementwise_max(h01, zero2);
                h23 = __builtin_elementwise_max(h23, zero2);
                bb.u[half * 2 + 0] = pk2(h01[0], h01[1]);
                bb.u[half * 2 + 1] = pk2(h23[0], h23[1]);
            }
            bfrag[kb] = bb.v;
        }
        // ---- A: layer 2 MFMA, bias in C-init ----
        f32x4_t acc2[4];
#pragma unroll
        for (int mt = 0; mt < 4; ++mt) {
            f32x4_t c;
            c[0] = b2q[mt].x; c[1] = b2q[mt].y; c[2] = b2q[mt].z; c[3] = b2q[mt].w;
#pragma unroll
            for (int kb = 0; kb < 4; ++kb)
                c = __builtin_amdgcn_mfma_f32_16x16x32_bf16(a2[mt * 4 + kb], bfrag[kb], c, 0, 0, 0);
            acc2[mt] = c;
        }
        // ---- A: packed relu + pack + write h2 slot ng&1 ----
        unsigned short* slot = h2w + (ng & 1) * 1152 + l15 * 72;
#pragma unroll
        for (int mt = 0; mt < 4; ++mt) {
            f32x2_t v01 = __builtin_elementwise_max((f32x2_t){acc2[mt][0], acc2[mt][1]}, zero2);
            f32x2_t v23 = __builtin_elementwise_max((f32x2_t){acc2[mt][2], acc2[mt][3]}, zero2);
            uint2 pk;
            pk.x = pk2(v01[0], v01[1]);
            pk.y = pk2(v23[0], v23[1]);
            *(uint2*)&slot[(mt * 16 + quad * 4) ^ sw] = pk;
        }
        // ---- B for previous group; flush batch when it completes ----
        if (ng > 0) {
            bphase(ng - 1);
            if (((ng - 1) & 7) == 7) cphase((ng - 1) >> 3);
        }
    }
    bphase(31);  // drain
    cphase(3);
}

extern "C" void kernel_launch(void* const* d_in, const int* in_sizes, int n_in,
                              void* d_out, int out_size, void* d_ws, size_t ws_size,
                              hipStream_t stream) {
    mlp_kernel<<<NPTS / 2048, 256, 0, stream>>>(
        (const float*)d_in[0], (const float*)d_in[1], (const float*)d_in[2],
        (const float*)d_in[3], (const float*)d_in[4], (const float*)d_in[5],
        (const float*)d_in[6], (const float*)d_in[7], (const float*)d_in[8],
        (float*)d_out);
}

// Round 12
// 139.893 us; speedup vs baseline: 1.0638x; 1.0112x over previous
//
#include <hip/hip_runtime.h>
#include <hip/hip_bf16.h>

// GeneratorSDF: latent-conditioned MLP SDF on a 128^3 grid (fp32 I/O).
// dims: 67 -> 128 -> 64 -> 32 -> 1 (relu, relu, relu, sigmoid)
//
// R12 = R11 + b3f prefetch. R11 (84us @ MfmaUtil 21 / VALUBusy 58): cycle
// audit says ~400 cyc serial per wave-ng vs ~180 issue -> stall-dominated.
// Biggest uncovered stall: bphase's two ds_read_b128 had read->use distance
// ~0 (~120 cyc LDS latency every ng). Hoist them to the TOP of iteration ng:
// slot (ng-1)&1 is disjoint from the slot A(ng) writes, and same-wave DS
// returns in order, so the whole A-phase (~250 cyc) covers the latency.
// Everything else byte-identical to R11 (2048 pts/block, grid 1024,
// batched cphase, LDS union, __launch_bounds__(256,2)).
// MFMA layouts (verified m89/m91): A[m=lane&15][k=quad*8+j],
// B[k=quad*8+j][n=lane&15], C/D row=quad*4+reg, col=lane&15.

#define NPTS (128 * 128 * 128)

typedef float f32x4_t __attribute__((ext_vector_type(4)));
typedef float f32x2_t __attribute__((ext_vector_type(2)));
typedef short bf16x8_t __attribute__((ext_vector_type(8)));

__device__ __forceinline__ unsigned pk2(float lo, float hi) {
    __hip_bfloat162 p = __float22bfloat162_rn(make_float2(lo, hi));
    unsigned u;
    __builtin_memcpy(&u, &p, sizeof(u));
    return u;
}

__global__ __launch_bounds__(256, 2) void mlp_kernel(
    const float* __restrict__ x,  const float* __restrict__ W1,
    const float* __restrict__ b1, const float* __restrict__ W2,
    const float* __restrict__ b2, const float* __restrict__ W3,
    const float* __restrict__ b3, const float* __restrict__ W4,
    const float* __restrict__ b4, float* __restrict__ out) {
    __shared__ __align__(16) float s_base[16][128];  // j-row: base+wa*pa+wb*pb_j
    __shared__ __align__(16) float s_wc[128];        // wc[k]
    __shared__ __align__(16) float s_b2[64];
    __shared__ __align__(16) float s_b3[32];
    __shared__ __align__(16) float s_w4[32];
    // Union (26.6 KB): staging = w2a[16][64][8] (shorts 0..8191) + w3a[4][64][8]
    // (8192..10239); runtime = h2 slots [w][2][16][72] (0..9215) + z floats
    // (shorts 9216..13311 = float[4][8][16][4] : w*512 + pg*64 + i*4 + q).
    __shared__ __align__(16) unsigned short s_u[13312];

    const int t = threadIdx.x;
    const int w = t >> 6;
    const int lane = t & 63;
    const int quad = lane >> 4;
    const int l15 = lane & 15;
    const float step = 2.0f / 127.0f;

    // ================= per-block prep =================
    if (t < 128) {
        const float* w1row = W1 + t * 67;
        float s = b1[t];
#pragma unroll 8
        for (int c = 0; c < 64; ++c) s = fmaf(w1row[c], x[c], s);
        const float wa = w1row[64], wb = w1row[65], wc = w1row[66];
        const float pa = -1.0f + step * (float)(blockIdx.x >> 3);   // gi
        const float base = fmaf(wa, pa, s);
        const int gj0 = (blockIdx.x & 7) * 16;
        s_wc[t] = wc;
#pragma unroll
        for (int j = 0; j < 16; ++j) {
            const float pb = -1.0f + step * (float)(gj0 + j);
            s_base[j][t] = fmaf(wb, pb, base);
        }
    }
    // W2 [64][128] -> bf16 A-frag staging
    const float2* W2v = (const float2*)W2;
#pragma unroll
    for (int it = 0; it < 16; ++it) {
        int pidx = t + 256 * it;
        int idx2 = pidx * 2;
        int o = idx2 >> 7, k = idx2 & 127;
        int mt = o >> 4, lm = o & 15;
        int kb = k >> 5, q = (k >> 3) & 3, jj = k & 7;
        float2 v = W2v[pidx];
        *(unsigned*)&s_u[(mt * 4 + kb) * 512 + (q * 16 + lm) * 8 + jj] = pk2(v.x, v.y);
    }
    // W3 [32][64] -> bf16 A-frag staging
    const float2* W3v = (const float2*)W3;
#pragma unroll
    for (int it = 0; it < 4; ++it) {
        int pidx = t + 256 * it;
        int idx2 = pidx * 2;
        int o = idx2 >> 6, k = idx2 & 63;
        int mt = o >> 4, lm = o & 15;
        int kb = k >> 5, q = (k >> 3) & 3, jj = k & 7;
        float2 v = W3v[pidx];
        *(unsigned*)&s_u[8192 + (mt * 2 + kb) * 512 + (q * 16 + lm) * 8 + jj] = pk2(v.x, v.y);
    }
    if (t < 64) s_b2[t] = b2[t];
    if (t < 32) {
        s_b3[t] = b3[t];
        s_w4[t] = W4[t];
    }
    const float bias4 = b4[0];
    __syncthreads();

    // ================= per-wave fragment preload =================
    bf16x8_t a2[16];
#pragma unroll
    for (int f = 0; f < 16; ++f) a2[f] = *(const bf16x8_t*)&s_u[f * 512 + lane * 8];
    bf16x8_t a3[4];
#pragma unroll
    for (int f = 0; f < 4; ++f) a3[f] = *(const bf16x8_t*)&s_u[8192 + f * 512 + lane * 8];
    float4 b2q[4];
#pragma unroll
    for (int mt = 0; mt < 4; ++mt) b2q[mt] = *(const float4*)&s_b2[mt * 16 + quad * 4];
    float4 b3q[2];
    f32x2_t w4lo[2], w4hi[2];
#pragma unroll
    for (int mt = 0; mt < 2; ++mt) {
        b3q[mt] = *(const float4*)&s_b3[mt * 16 + quad * 4];
        float4 wq = *(const float4*)&s_w4[mt * 16 + quad * 4];
        w4lo[mt][0] = wq.x; w4lo[mt][1] = wq.y;
        w4hi[mt][0] = wq.z; w4hi[mt][1] = wq.w;
    }
    __syncthreads();  // union handoff: staging -> h2/z scratch

    const int sw = (l15 & 1) * 32;                    // h2 channel swizzle (shorts)
    unsigned short* h2w = &s_u[w * 2 * 1152];         // 2 slots x 16 pts x 72 shorts
    float* zf = (float*)&s_u[9216];                   // [w][pg&7][i][q]
    const f32x2_t zero2 = {0.0f, 0.0f};
    const int outbase = blockIdx.x * 2048 + w * 512;

    // B-phase tail: layer 3 + w4-dot using PRELOADED h2 fragments
    auto bphase = [&](int pg, bf16x8_t b3f0, bf16x8_t b3f1) {
        f32x2_t z2 = zero2;
#pragma unroll
        for (int mt = 0; mt < 2; ++mt) {
            f32x4_t c;
            c[0] = b3q[mt].x; c[1] = b3q[mt].y; c[2] = b3q[mt].z; c[3] = b3q[mt].w;
            c = __builtin_amdgcn_mfma_f32_16x16x32_bf16(a3[mt * 2 + 0], b3f0, c, 0, 0, 0);
            c = __builtin_amdgcn_mfma_f32_16x16x32_bf16(a3[mt * 2 + 1], b3f1, c, 0, 0, 0);
            f32x2_t h01 = __builtin_elementwise_max((f32x2_t){c[0], c[1]}, zero2);
            f32x2_t h23 = __builtin_elementwise_max((f32x2_t){c[2], c[3]}, zero2);
            z2 = __builtin_elementwise_fma(w4lo[mt], h01, z2);
            z2 = __builtin_elementwise_fma(w4hi[mt], h23, z2);
        }
        zf[w * 512 + (pg & 7) * 64 + l15 * 4 + quad] = z2[0] + z2[1];
    };
    // phase C: batched reduce + sigmoid + coalesced store for an 8-ng batch
    auto cphase = [&](int batch) {
#pragma unroll
        for (int half = 0; half < 2; ++half) {
            const int p = lane + 64 * half;   // point within this batch's 128
            const int pg = p >> 4, i = p & 15;
            float4 v = *(const float4*)&zf[w * 512 + pg * 64 + i * 4];
            float z = (v.x + v.y) + (v.z + v.w) + bias4;
            out[outbase + batch * 128 + p] = 1.0f / (1.0f + __expf(-z));
        }
    };

    // ========== pipelined main loop: prefetch b3f(ng-1), A(ng), B(ng-1) ==========
#pragma unroll 2
    for (int ng = 0; ng < 32; ++ng) {
        // ---- prefetch h2 fragments for bphase(ng-1): issued FIRST so the whole
        // A-phase covers the ~120cyc LDS latency (slot (ng-1)&1 is disjoint from
        // the slot A(ng) writes; same-wave DS completes in order) ----
        bf16x8_t b3f0, b3f1;
        if (ng > 0) {
            const unsigned short* pslot = h2w + ((ng - 1) & 1) * 1152 + l15 * 72;
            b3f0 = *(const bf16x8_t*)&pslot[(0 ^ sw) + quad * 8];
            b3f1 = *(const bf16x8_t*)&pslot[(32 ^ sw) + quad * 8];
        }

        const float* dj = &s_base[w * 4 + (ng >> 3)][0];
        const float pc = fmaf(step, (float)(((ng & 7) * 16) + l15), -1.0f);
        const f32x2_t pc2 = {pc, pc};

        // ---- A: h1 into B-fragments via packed fma/max ----
        bf16x8_t bfrag[4];
#pragma unroll
        for (int kb = 0; kb < 4; ++kb) {
            union { bf16x8_t v; unsigned u[4]; } bb;
#pragma unroll
            for (int half = 0; half < 2; ++half) {
                const int o = kb * 32 + quad * 8 + half * 4;
                float4 bs = *(const float4*)&dj[o];
                float4 wc4 = *(const float4*)&s_wc[o];
                f32x2_t h01 = __builtin_elementwise_fma(
                    (f32x2_t){wc4.x, wc4.y}, pc2, (f32x2_t){bs.x, bs.y});
                f32x2_t h23 = __builtin_elementwise_fma(
                    (f32x2_t){wc4.z, wc4.w}, pc2, (f32x2_t){bs.z, bs.w});
                h01 = __builtin_elementwise_max(h01, zero2);
                h23 = __builtin_elementwise_max(h23, zero2);
                bb.u[half * 2 + 0] = pk2(h01[0], h01[1]);
                bb.u[half * 2 + 1] = pk2(h23[0], h23[1]);
            }
            bfrag[kb] = bb.v;
        }
        // ---- A: layer 2 MFMA, bias in C-init ----
        f32x4_t acc2[4];
#pragma unroll
        for (int mt = 0; mt < 4; ++mt) {
            f32x4_t c;
            c[0] = b2q[mt].x; c[1] = b2q[mt].y; c[2] = b2q[mt].z; c[3] = b2q[mt].w;
#pragma unroll
            for (int kb = 0; kb < 4; ++kb)
                c = __builtin_amdgcn_mfma_f32_16x16x32_bf16(a2[mt * 4 + kb], bfrag[kb], c, 0, 0, 0);
            acc2[mt] = c;
        }
        // ---- A: packed relu + pack + write h2 slot ng&1 ----
        unsigned short* slot = h2w + (ng & 1) * 1152 + l15 * 72;
#pragma unroll
        for (int mt = 0; mt < 4; ++mt) {
            f32x2_t v01 = __builtin_elementwise_max((f32x2_t){acc2[mt][0], acc2[mt][1]}, zero2);
            f32x2_t v23 = __builtin_elementwise_max((f32x2_t){acc2[mt][2], acc2[mt][3]}, zero2);
            uint2 pk;
            pk.x = pk2(v01[0], v01[1]);
            pk.y = pk2(v23[0], v23[1]);
            *(uint2*)&slot[(mt * 16 + quad * 4) ^ sw] = pk;
        }
        // ---- B for previous group (fragments already in registers) ----
        if (ng > 0) {
            bphase(ng - 1, b3f0, b3f1);
            if (((ng - 1) & 7) == 7) cphase((ng - 1) >> 3);
        }
    }
    {   // drain: bphase(31) with direct reads
        const unsigned short* pslot = h2w + (31 & 1) * 1152 + l15 * 72;
        bf16x8_t b3f0 = *(const bf16x8_t*)&pslot[(0 ^ sw) + quad * 8];
        bf16x8_t b3f1 = *(const bf16x8_t*)&pslot[(32 ^ sw) + quad * 8];
        bphase(31, b3f0, b3f1);
        cphase(3);
    }
}

extern "C" void kernel_launch(void* const* d_in, const int* in_sizes, int n_in,
                              void* d_out, int out_size, void* d_ws, size_t ws_size,
                              hipStream_t stream) {
    mlp_kernel<<<NPTS / 2048, 256, 0, stream>>>(
        (const float*)d_in[0], (const float*)d_in[1], (const float*)d_in[2],
        (const float*)d_in[3], (const float*)d_in[4], (const float*)d_in[5],
        (const float*)d_in[6], (const float*)d_in[7], (const float*)d_in[8],
        (float*)d_out);
}

// Round 13
// 139.754 us; speedup vs baseline: 1.0649x; 1.0010x over previous
//
#include <hip/hip_runtime.h>
#include <hip/hip_bf16.h>

// GeneratorSDF: latent-conditioned MLP SDF on a 128^3 grid (fp32 I/O).
// dims: 67 -> 128 -> 64 -> 32 -> 1 (relu, relu, relu, sigmoid)
//
// R13: LDS-PIPE THROUGHPUT theory. R9 (VALU-25%) neutral, R12 (DS latency
// reposition) neutral, R11 (conflicts halved) won => the shared DS pipe is
// saturated: 16 ds_read_b128/ng of ng-invariant tables = ~70% of DS traffic
// (~245 of ~400 cyc/wave-ng). Fix: jrow-outer loop; dj table (32 f/lane, per
// jrow) + wc table (32 f/lane, invariant) live in VGPRs, pinned with an empty
// asm volatile barrier so the allocator CANNOT sink the loads back into the
// loop (R10's defeat). Accept 2 waves/SIMD (VGPR ~200). In-loop DS drops to
// 4 h2-writes + 2 b3f-reads + 1 zf-write per ng.
// Everything else from R11/R12: 2048 pts/block (grid 1024), pipelined h2
// double-buffer, b3f prefetch, batched cphase, LDS union, bounds (256,2).
// MFMA layouts (verified m89/m91): A[m=lane&15][k=quad*8+j],
// B[k=quad*8+j][n=lane&15], C/D row=quad*4+reg, col=lane&15.

#define NPTS (128 * 128 * 128)

typedef float f32x4_t __attribute__((ext_vector_type(4)));
typedef float f32x2_t __attribute__((ext_vector_type(2)));
typedef short bf16x8_t __attribute__((ext_vector_type(8)));

__device__ __forceinline__ unsigned pk2(float lo, float hi) {
    __hip_bfloat162 p = __float22bfloat162_rn(make_float2(lo, hi));
    unsigned u;
    __builtin_memcpy(&u, &p, sizeof(u));
    return u;
}

__global__ __launch_bounds__(256, 2) void mlp_kernel(
    const float* __restrict__ x,  const float* __restrict__ W1,
    const float* __restrict__ b1, const float* __restrict__ W2,
    const float* __restrict__ b2, const float* __restrict__ W3,
    const float* __restrict__ b3, const float* __restrict__ W4,
    const float* __restrict__ b4, float* __restrict__ out) {
    __shared__ __align__(16) float s_base[16][128];  // j-row: base+wa*pa+wb*pb_j
    __shared__ __align__(16) float s_wc[128];        // wc[k]
    __shared__ __align__(16) float s_b2[64];
    __shared__ __align__(16) float s_b3[32];
    __shared__ __align__(16) float s_w4[32];
    // Union (26.6 KB): staging = w2a[16][64][8] (shorts 0..8191) + w3a[4][64][8]
    // (8192..10239); runtime = h2 slots [w][2][16][72] (0..9215) + z floats
    // (shorts 9216..13311 = float[4][8][16][4] : w*512 + pg*64 + i*4 + q).
    __shared__ __align__(16) unsigned short s_u[13312];

    const int t = threadIdx.x;
    const int w = t >> 6;
    const int lane = t & 63;
    const int quad = lane >> 4;
    const int l15 = lane & 15;
    const float step = 2.0f / 127.0f;

    // ================= per-block prep =================
    if (t < 128) {
        const float* w1row = W1 + t * 67;
        float s = b1[t];
#pragma unroll 8
        for (int c = 0; c < 64; ++c) s = fmaf(w1row[c], x[c], s);
        const float wa = w1row[64], wb = w1row[65], wc = w1row[66];
        const float pa = -1.0f + step * (float)(blockIdx.x >> 3);   // gi
        const float base = fmaf(wa, pa, s);
        const int gj0 = (blockIdx.x & 7) * 16;
        s_wc[t] = wc;
#pragma unroll
        for (int j = 0; j < 16; ++j) {
            const float pb = -1.0f + step * (float)(gj0 + j);
            s_base[j][t] = fmaf(wb, pb, base);
        }
    }
    // W2 [64][128] -> bf16 A-frag staging
    const float2* W2v = (const float2*)W2;
#pragma unroll
    for (int it = 0; it < 16; ++it) {
        int pidx = t + 256 * it;
        int idx2 = pidx * 2;
        int o = idx2 >> 7, k = idx2 & 127;
        int mt = o >> 4, lm = o & 15;
        int kb = k >> 5, q = (k >> 3) & 3, jj = k & 7;
        float2 v = W2v[pidx];
        *(unsigned*)&s_u[(mt * 4 + kb) * 512 + (q * 16 + lm) * 8 + jj] = pk2(v.x, v.y);
    }
    // W3 [32][64] -> bf16 A-frag staging
    const float2* W3v = (const float2*)W3;
#pragma unroll
    for (int it = 0; it < 4; ++it) {
        int pidx = t + 256 * it;
        int idx2 = pidx * 2;
        int o = idx2 >> 6, k = idx2 & 63;
        int mt = o >> 4, lm = o & 15;
        int kb = k >> 5, q = (k >> 3) & 3, jj = k & 7;
        float2 v = W3v[pidx];
        *(unsigned*)&s_u[8192 + (mt * 2 + kb) * 512 + (q * 16 + lm) * 8 + jj] = pk2(v.x, v.y);
    }
    if (t < 64) s_b2[t] = b2[t];
    if (t < 32) {
        s_b3[t] = b3[t];
        s_w4[t] = W4[t];
    }
    const float bias4 = b4[0];
    __syncthreads();

    // ================= per-wave fragment preload =================
    bf16x8_t a2[16];
#pragma unroll
    for (int f = 0; f < 16; ++f) a2[f] = *(const bf16x8_t*)&s_u[f * 512 + lane * 8];
    bf16x8_t a3[4];
#pragma unroll
    for (int f = 0; f < 4; ++f) a3[f] = *(const bf16x8_t*)&s_u[8192 + f * 512 + lane * 8];
    float4 b2q[4];
#pragma unroll
    for (int mt = 0; mt < 4; ++mt) b2q[mt] = *(const float4*)&s_b2[mt * 16 + quad * 4];
    float4 b3q[2];
    f32x2_t w4lo[2], w4hi[2];
#pragma unroll
    for (int mt = 0; mt < 2; ++mt) {
        b3q[mt] = *(const float4*)&s_b3[mt * 16 + quad * 4];
        float4 wq = *(const float4*)&s_w4[mt * 16 + quad * 4];
        w4lo[mt][0] = wq.x; w4lo[mt][1] = wq.y;
        w4hi[mt][0] = wq.z; w4hi[mt][1] = wq.w;
    }
    // ---- wc table: loop-invariant, 32 floats/lane, pinned in VGPRs ----
    float tw[32];
#pragma unroll
    for (int kb = 0; kb < 4; ++kb) {
#pragma unroll
        for (int half = 0; half < 2; ++half) {
            float4 v = *(const float4*)&s_wc[kb * 32 + quad * 8 + half * 4];
            const int i = kb * 8 + half * 4;
            tw[i] = v.x; tw[i + 1] = v.y; tw[i + 2] = v.z; tw[i + 3] = v.w;
        }
    }
#pragma unroll
    for (int i = 0; i < 32; ++i) asm volatile("" : "+v"(tw[i]));  // pin: no re-load
    __syncthreads();  // union handoff: staging -> h2/z scratch

    const int sw = (l15 & 1) * 32;                    // h2 channel swizzle (shorts)
    unsigned short* h2w = &s_u[w * 2 * 1152];         // 2 slots x 16 pts x 72 shorts
    float* zf = (float*)&s_u[9216];                   // [w][pg&7][i][q]
    const f32x2_t zero2 = {0.0f, 0.0f};
    const int outbase = blockIdx.x * 2048 + w * 512;

    // B-phase tail: layer 3 + w4-dot using PRELOADED h2 fragments
    auto bphase = [&](int pg, bf16x8_t b3f0, bf16x8_t b3f1) {
        f32x2_t z2 = zero2;
#pragma unroll
        for (int mt = 0; mt < 2; ++mt) {
            f32x4_t c;
            c[0] = b3q[mt].x; c[1] = b3q[mt].y; c[2] = b3q[mt].z; c[3] = b3q[mt].w;
            c = __builtin_amdgcn_mfma_f32_16x16x32_bf16(a3[mt * 2 + 0], b3f0, c, 0, 0, 0);
            c = __builtin_amdgcn_mfma_f32_16x16x32_bf16(a3[mt * 2 + 1], b3f1, c, 0, 0, 0);
            f32x2_t h01 = __builtin_elementwise_max((f32x2_t){c[0], c[1]}, zero2);
            f32x2_t h23 = __builtin_elementwise_max((f32x2_t){c[2], c[3]}, zero2);
            z2 = __builtin_elementwise_fma(w4lo[mt], h01, z2);
            z2 = __builtin_elementwise_fma(w4hi[mt], h23, z2);
        }
        zf[w * 512 + (pg & 7) * 64 + l15 * 4 + quad] = z2[0] + z2[1];
    };
    // phase C: batched reduce + sigmoid + coalesced store for an 8-ng batch
    auto cphase = [&](int batch) {
#pragma unroll
        for (int half = 0; half < 2; ++half) {
            const int p = lane + 64 * half;   // point within this batch's 128
            const int pg = p >> 4, i = p & 15;
            float4 v = *(const float4*)&zf[w * 512 + pg * 64 + i * 4];
            float z = (v.x + v.y) + (v.z + v.w) + bias4;
            out[outbase + batch * 128 + p] = 1.0f / (1.0f + __expf(-z));
        }
    };

    // ========== jrow-outer main loop ==========
    for (int jrow = 0; jrow < 4; ++jrow) {
        // ---- dj table for this jrow: 32 floats/lane, pinned in VGPRs ----
        const float* dj = &s_base[w * 4 + jrow][0];
        float tb[32];
#pragma unroll
        for (int kb = 0; kb < 4; ++kb) {
#pragma unroll
            for (int half = 0; half < 2; ++half) {
                float4 v = *(const float4*)&dj[kb * 32 + quad * 8 + half * 4];
                const int i = kb * 8 + half * 4;
                tb[i] = v.x; tb[i + 1] = v.y; tb[i + 2] = v.z; tb[i + 3] = v.w;
            }
        }
#pragma unroll
        for (int i = 0; i < 32; ++i) asm volatile("" : "+v"(tb[i]));  // pin

#pragma unroll 2
        for (int pg = 0; pg < 8; ++pg) {
            const int ng = jrow * 8 + pg;
            // ---- prefetch h2 fragments for bphase(ng-1) ----
            bf16x8_t b3f0, b3f1;
            if (ng > 0) {
                const unsigned short* pslot = h2w + ((ng - 1) & 1) * 1152 + l15 * 72;
                b3f0 = *(const bf16x8_t*)&pslot[(0 ^ sw) + quad * 8];
                b3f1 = *(const bf16x8_t*)&pslot[(32 ^ sw) + quad * 8];
            }

            const float pc = fmaf(step, (float)((pg * 16) + l15), -1.0f);
            const f32x2_t pc2 = {pc, pc};

            // ---- A: h1 into B-fragments, tables in registers (no DS) ----
            bf16x8_t bfrag[4];
#pragma unroll
            for (int kb = 0; kb < 4; ++kb) {
                union { bf16x8_t v; unsigned u[4]; } bb;
#pragma unroll
                for (int half = 0; half < 2; ++half) {
                    const int i = kb * 8 + half * 4;
                    f32x2_t h01 = __builtin_elementwise_fma(
                        (f32x2_t){tw[i], tw[i + 1]}, pc2, (f32x2_t){tb[i], tb[i + 1]});
                    f32x2_t h23 = __builtin_elementwise_fma(
                        (f32x2_t){tw[i + 2], tw[i + 3]}, pc2, (f32x2_t){tb[i + 2], tb[i + 3]});
                    h01 = __builtin_elementwise_max(h01, zero2);
                    h23 = __builtin_elementwise_max(h23, zero2);
                    bb.u[half * 2 + 0] = pk2(h01[0], h01[1]);
                    bb.u[half * 2 + 1] = pk2(h23[0], h23[1]);
                }
                bfrag[kb] = bb.v;
            }
            // ---- A: layer 2 MFMA, bias in C-init ----
            f32x4_t acc2[4];
#pragma unroll
            for (int mt = 0; mt < 4; ++mt) {
                f32x4_t c;
                c[0] = b2q[mt].x; c[1] = b2q[mt].y; c[2] = b2q[mt].z; c[3] = b2q[mt].w;
#pragma unroll
                for (int kb = 0; kb < 4; ++kb)
                    c = __builtin_amdgcn_mfma_f32_16x16x32_bf16(a2[mt * 4 + kb], bfrag[kb], c, 0, 0, 0);
                acc2[mt] = c;
            }
            // ---- A: packed relu + pack + write h2 slot ng&1 ----
            unsigned short* slot = h2w + (ng & 1) * 1152 + l15 * 72;
#pragma unroll
            for (int mt = 0; mt < 4; ++mt) {
                f32x2_t v01 = __builtin_elementwise_max((f32x2_t){acc2[mt][0], acc2[mt][1]}, zero2);
                f32x2_t v23 = __builtin_elementwise_max((f32x2_t){acc2[mt][2], acc2[mt][3]}, zero2);
                uint2 pk;
                pk.x = pk2(v01[0], v01[1]);
                pk.y = pk2(v23[0], v23[1]);
                *(uint2*)&slot[(mt * 16 + quad * 4) ^ sw] = pk;
            }
            // ---- B for previous group (fragments already in registers) ----
            if (ng > 0) {
                bphase(ng - 1, b3f0, b3f1);
                if (((ng - 1) & 7) == 7) cphase((ng - 1) >> 3);
            }
        }
    }
    {   // drain: bphase(31) with direct reads
        const unsigned short* pslot = h2w + (31 & 1) * 1152 + l15 * 72;
        bf16x8_t b3f0 = *(const bf16x8_t*)&pslot[(0 ^ sw) + quad * 8];
        bf16x8_t b3f1 = *(const bf16x8_t*)&pslot[(32 ^ sw) + quad * 8];
        bphase(31, b3f0, b3f1);
        cphase(3);
    }
}

extern "C" void kernel_launch(void* const* d_in, const int* in_sizes, int n_in,
                              void* d_out, int out_size, void* d_ws, size_t ws_size,
                              hipStream_t stream) {
    mlp_kernel<<<NPTS / 2048, 256, 0, stream>>>(
        (const float*)d_in[0], (const float*)d_in[1], (const float*)d_in[2],
        (const float*)d_in[3], (const float*)d_in[4], (const float*)d_in[5],
        (const float*)d_in[6], (const float*)d_in[7], (const float*)d_in[8],
        (float*)d_out);
}

// Round 14
// 135.682 us; speedup vs baseline: 1.0968x; 1.0300x over previous
//
#include <hip/hip_runtime.h>
#include <hip/hip_bf16.h>

// GeneratorSDF: latent-conditioned MLP SDF on a 128^3 grid (fp32 I/O).
// dims: 67 -> 128 -> 64 -> 32 -> 1 (relu, relu, relu, sigmoid)
//
// R14 = R13 + cheap bf16 pack. Counter forensics: VALUBusy 60% => ~470 VALU
// instr/wave-ng vs ~110 at source level. The 4x expansion is pk2:
// __float22bfloat162_rn is a software-RNE sequence (~8-10 instr/pair), called
// 24x/ng. Replace with round-half-up: (u+0x8000) per half + one v_perm_b32
// (__builtin_amdgcn_perm) = 3 instr/pair. Max err 1 ulp bf16 (ties only
// differ vs RNE); current absmax margin is 4.8x under threshold.
// Everything else identical to R13 (2048 pts/block, reg-pinned dj/wc tables,
// pipelined h2 double-buffer, b3f prefetch, batched cphase, LDS union,
// __launch_bounds__(256,2)).
// MFMA layouts (verified m89/m91): A[m=lane&15][k=quad*8+j],
// B[k=quad*8+j][n=lane&15], C/D row=quad*4+reg, col=lane&15.

#define NPTS (128 * 128 * 128)

typedef float f32x4_t __attribute__((ext_vector_type(4)));
typedef float f32x2_t __attribute__((ext_vector_type(2)));
typedef short bf16x8_t __attribute__((ext_vector_type(8)));

// f32x2 -> packed bf16x2, round-half-up: 2x v_add_u32 + 1x v_perm_b32.
__device__ __forceinline__ unsigned pk2(float lo, float hi) {
    unsigned a, b;
    __builtin_memcpy(&a, &lo, 4);
    __builtin_memcpy(&b, &hi, 4);
    return __builtin_amdgcn_perm(b + 0x8000u, a + 0x8000u, 0x07060302u);
}

__global__ __launch_bounds__(256, 2) void mlp_kernel(
    const float* __restrict__ x,  const float* __restrict__ W1,
    const float* __restrict__ b1, const float* __restrict__ W2,
    const float* __restrict__ b2, const float* __restrict__ W3,
    const float* __restrict__ b3, const float* __restrict__ W4,
    const float* __restrict__ b4, float* __restrict__ out) {
    __shared__ __align__(16) float s_base[16][128];  // j-row: base+wa*pa+wb*pb_j
    __shared__ __align__(16) float s_wc[128];        // wc[k]
    __shared__ __align__(16) float s_b2[64];
    __shared__ __align__(16) float s_b3[32];
    __shared__ __align__(16) float s_w4[32];
    // Union (26.6 KB): staging = w2a[16][64][8] (shorts 0..8191) + w3a[4][64][8]
    // (8192..10239); runtime = h2 slots [w][2][16][72] (0..9215) + z floats
    // (shorts 9216..13311 = float[4][8][16][4] : w*512 + pg*64 + i*4 + q).
    __shared__ __align__(16) unsigned short s_u[13312];

    const int t = threadIdx.x;
    const int w = t >> 6;
    const int lane = t & 63;
    const int quad = lane >> 4;
    const int l15 = lane & 15;
    const float step = 2.0f / 127.0f;

    // ================= per-block prep =================
    if (t < 128) {
        const float* w1row = W1 + t * 67;
        float s = b1[t];
#pragma unroll 8
        for (int c = 0; c < 64; ++c) s = fmaf(w1row[c], x[c], s);
        const float wa = w1row[64], wb = w1row[65], wc = w1row[66];
        const float pa = -1.0f + step * (float)(blockIdx.x >> 3);   // gi
        const float base = fmaf(wa, pa, s);
        const int gj0 = (blockIdx.x & 7) * 16;
        s_wc[t] = wc;
#pragma unroll
        for (int j = 0; j < 16; ++j) {
            const float pb = -1.0f + step * (float)(gj0 + j);
            s_base[j][t] = fmaf(wb, pb, base);
        }
    }
    // W2 [64][128] -> bf16 A-frag staging
    const float2* W2v = (const float2*)W2;
#pragma unroll
    for (int it = 0; it < 16; ++it) {
        int pidx = t + 256 * it;
        int idx2 = pidx * 2;
        int o = idx2 >> 7, k = idx2 & 127;
        int mt = o >> 4, lm = o & 15;
        int kb = k >> 5, q = (k >> 3) & 3, jj = k & 7;
        float2 v = W2v[pidx];
        *(unsigned*)&s_u[(mt * 4 + kb) * 512 + (q * 16 + lm) * 8 + jj] = pk2(v.x, v.y);
    }
    // W3 [32][64] -> bf16 A-frag staging
    const float2* W3v = (const float2*)W3;
#pragma unroll
    for (int it = 0; it < 4; ++it) {
        int pidx = t + 256 * it;
        int idx2 = pidx * 2;
        int o = idx2 >> 6, k = idx2 & 63;
        int mt = o >> 4, lm = o & 15;
        int kb = k >> 5, q = (k >> 3) & 3, jj = k & 7;
        float2 v = W3v[pidx];
        *(unsigned*)&s_u[8192 + (mt * 2 + kb) * 512 + (q * 16 + lm) * 8 + jj] = pk2(v.x, v.y);
    }
    if (t < 64) s_b2[t] = b2[t];
    if (t < 32) {
        s_b3[t] = b3[t];
        s_w4[t] = W4[t];
    }
    const float bias4 = b4[0];
    __syncthreads();

    // ================= per-wave fragment preload =================
    bf16x8_t a2[16];
#pragma unroll
    for (int f = 0; f < 16; ++f) a2[f] = *(const bf16x8_t*)&s_u[f * 512 + lane * 8];
    bf16x8_t a3[4];
#pragma unroll
    for (int f = 0; f < 4; ++f) a3[f] = *(const bf16x8_t*)&s_u[8192 + f * 512 + lane * 8];
    float4 b2q[4];
#pragma unroll
    for (int mt = 0; mt < 4; ++mt) b2q[mt] = *(const float4*)&s_b2[mt * 16 + quad * 4];
    float4 b3q[2];
    f32x2_t w4lo[2], w4hi[2];
#pragma unroll
    for (int mt = 0; mt < 2; ++mt) {
        b3q[mt] = *(const float4*)&s_b3[mt * 16 + quad * 4];
        float4 wq = *(const float4*)&s_w4[mt * 16 + quad * 4];
        w4lo[mt][0] = wq.x; w4lo[mt][1] = wq.y;
        w4hi[mt][0] = wq.z; w4hi[mt][1] = wq.w;
    }
    // ---- wc table: loop-invariant, 32 floats/lane, pinned in VGPRs ----
    float tw[32];
#pragma unroll
    for (int kb = 0; kb < 4; ++kb) {
#pragma unroll
        for (int half = 0; half < 2; ++half) {
            float4 v = *(const float4*)&s_wc[kb * 32 + quad * 8 + half * 4];
            const int i = kb * 8 + half * 4;
            tw[i] = v.x; tw[i + 1] = v.y; tw[i + 2] = v.z; tw[i + 3] = v.w;
        }
    }
#pragma unroll
    for (int i = 0; i < 32; ++i) asm volatile("" : "+v"(tw[i]));  // pin: no re-load
    __syncthreads();  // union handoff: staging -> h2/z scratch

    const int sw = (l15 & 1) * 32;                    // h2 channel swizzle (shorts)
    unsigned short* h2w = &s_u[w * 2 * 1152];         // 2 slots x 16 pts x 72 shorts
    float* zf = (float*)&s_u[9216];                   // [w][pg&7][i][q]
    const f32x2_t zero2 = {0.0f, 0.0f};
    const int outbase = blockIdx.x * 2048 + w * 512;

    // B-phase tail: layer 3 + w4-dot using PRELOADED h2 fragments
    auto bphase = [&](int pg, bf16x8_t b3f0, bf16x8_t b3f1) {
        f32x2_t z2 = zero2;
#pragma unroll
        for (int mt = 0; mt < 2; ++mt) {
            f32x4_t c;
            c[0] = b3q[mt].x; c[1] = b3q[mt].y; c[2] = b3q[mt].z; c[3] = b3q[mt].w;
            c = __builtin_amdgcn_mfma_f32_16x16x32_bf16(a3[mt * 2 + 0], b3f0, c, 0, 0, 0);
            c = __builtin_amdgcn_mfma_f32_16x16x32_bf16(a3[mt * 2 + 1], b3f1, c, 0, 0, 0);
            f32x2_t h01 = __builtin_elementwise_max((f32x2_t){c[0], c[1]}, zero2);
            f32x2_t h23 = __builtin_elementwise_max((f32x2_t){c[2], c[3]}, zero2);
            z2 = __builtin_elementwise_fma(w4lo[mt], h01, z2);
            z2 = __builtin_elementwise_fma(w4hi[mt], h23, z2);
        }
        zf[w * 512 + (pg & 7) * 64 + l15 * 4 + quad] = z2[0] + z2[1];
    };
    // phase C: batched reduce + sigmoid + coalesced store for an 8-ng batch
    auto cphase = [&](int batch) {
#pragma unroll
        for (int half = 0; half < 2; ++half) {
            const int p = lane + 64 * half;   // point within this batch's 128
            const int pg = p >> 4, i = p & 15;
            float4 v = *(const float4*)&zf[w * 512 + pg * 64 + i * 4];
            float z = (v.x + v.y) + (v.z + v.w) + bias4;
            out[outbase + batch * 128 + p] = 1.0f / (1.0f + __expf(-z));
        }
    };

    // ========== jrow-outer main loop ==========
    for (int jrow = 0; jrow < 4; ++jrow) {
        // ---- dj table for this jrow: 32 floats/lane, pinned in VGPRs ----
        const float* dj = &s_base[w * 4 + jrow][0];
        float tb[32];
#pragma unroll
        for (int kb = 0; kb < 4; ++kb) {
#pragma unroll
            for (int half = 0; half < 2; ++half) {
                float4 v = *(const float4*)&dj[kb * 32 + quad * 8 + half * 4];
                const int i = kb * 8 + half * 4;
                tb[i] = v.x; tb[i + 1] = v.y; tb[i + 2] = v.z; tb[i + 3] = v.w;
            }
        }
#pragma unroll
        for (int i = 0; i < 32; ++i) asm volatile("" : "+v"(tb[i]));  // pin

#pragma unroll 2
        for (int pg = 0; pg < 8; ++pg) {
            const int ng = jrow * 8 + pg;
            // ---- prefetch h2 fragments for bphase(ng-1) ----
            bf16x8_t b3f0, b3f1;
            if (ng > 0) {
                const unsigned short* pslot = h2w + ((ng - 1) & 1) * 1152 + l15 * 72;
                b3f0 = *(const bf16x8_t*)&pslot[(0 ^ sw) + quad * 8];
                b3f1 = *(const bf16x8_t*)&pslot[(32 ^ sw) + quad * 8];
            }

            const float pc = fmaf(step, (float)((pg * 16) + l15), -1.0f);
            const f32x2_t pc2 = {pc, pc};

            // ---- A: h1 into B-fragments, tables in registers (no DS) ----
            bf16x8_t bfrag[4];
#pragma unroll
            for (int kb = 0; kb < 4; ++kb) {
                union { bf16x8_t v; unsigned u[4]; } bb;
#pragma unroll
                for (int half = 0; half < 2; ++half) {
                    const int i = kb * 8 + half * 4;
                    f32x2_t h01 = __builtin_elementwise_fma(
                        (f32x2_t){tw[i], tw[i + 1]}, pc2, (f32x2_t){tb[i], tb[i + 1]});
                    f32x2_t h23 = __builtin_elementwise_fma(
                        (f32x2_t){tw[i + 2], tw[i + 3]}, pc2, (f32x2_t){tb[i + 2], tb[i + 3]});
                    h01 = __builtin_elementwise_max(h01, zero2);
                    h23 = __builtin_elementwise_max(h23, zero2);
                    bb.u[half * 2 + 0] = pk2(h01[0], h01[1]);
                    bb.u[half * 2 + 1] = pk2(h23[0], h23[1]);
                }
                bfrag[kb] = bb.v;
            }
            // ---- A: layer 2 MFMA, bias in C-init ----
            f32x4_t acc2[4];
#pragma unroll
            for (int mt = 0; mt < 4; ++mt) {
                f32x4_t c;
                c[0] = b2q[mt].x; c[1] = b2q[mt].y; c[2] = b2q[mt].z; c[3] = b2q[mt].w;
#pragma unroll
                for (int kb = 0; kb < 4; ++kb)
                    c = __builtin_amdgcn_mfma_f32_16x16x32_bf16(a2[mt * 4 + kb], bfrag[kb], c, 0, 0, 0);
                acc2[mt] = c;
            }
            // ---- A: packed relu + pack + write h2 slot ng&1 ----
            unsigned short* slot = h2w + (ng & 1) * 1152 + l15 * 72;
#pragma unroll
            for (int mt = 0; mt < 4; ++mt) {
                f32x2_t v01 = __builtin_elementwise_max((f32x2_t){acc2[mt][0], acc2[mt][1]}, zero2);
                f32x2_t v23 = __builtin_elementwise_max((f32x2_t){acc2[mt][2], acc2[mt][3]}, zero2);
                uint2 pk;
                pk.x = pk2(v01[0], v01[1]);
                pk.y = pk2(v23[0], v23[1]);
                *(uint2*)&slot[(mt * 16 + quad * 4) ^ sw] = pk;
            }
            // ---- B for previous group (fragments already in registers) ----
            if (ng > 0) {
                bphase(ng - 1, b3f0, b3f1);
                if (((ng - 1) & 7) == 7) cphase((ng - 1) >> 3);
            }
        }
    }
    {   // drain: bphase(31) with direct reads
        const unsigned short* pslot = h2w + (31 & 1) * 1152 + l15 * 72;
        bf16x8_t b3f0 = *(const bf16x8_t*)&pslot[(0 ^ sw) + quad * 8];
        bf16x8_t b3f1 = *(const bf16x8_t*)&pslot[(32 ^ sw) + quad * 8];
        bphase(31, b3f0, b3f1);
        cphase(3);
    }
}

extern "C" void kernel_launch(void* const* d_in, const int* in_sizes, int n_in,
                              void* d_out, int out_size, void* d_ws, size_t ws_size,
                              hipStream_t stream) {
    mlp_kernel<<<NPTS / 2048, 256, 0, stream>>>(
        (const float*)d_in[0], (const float*)d_in[1], (const float*)d_in[2],
        (const float*)d_in[3], (const float*)d_in[4], (const float*)d_in[5],
        (const float*)d_in[6], (const float*)d_in[7], (const float*)d_in[8],
        (float*)d_out);
}